// Round 1
// baseline (11498.580 us; speedup 1.0000x reference)
//
#include <hip/hip_runtime.h>
#include <cstdint>
#include <cstddef>

#define B_DIM   64
#define T_DIM   256
#define ICD_DIM 2000
#define H_DIM   384
#define L_DIM   3
#define CH_DIM  128
#define W_WIN   10
#define M_DIM   (B_DIM * T_DIM)        // 16384
#define XO_DIM  (4 * H_DIM + 2 * L_DIM) // 1542
#define KCONV   (H_DIM * W_WIN)        // 3840

__device__ __forceinline__ float sigmoidf_(float x) { return 1.f / (1.f + expf(-x)); }

// ---------------------------------------------------------------------------
// small prep kernels
// ---------------------------------------------------------------------------
__global__ void bias2_kernel(const float* __restrict__ kernel_w, const float* __restrict__ kernel_b,
                             const float* __restrict__ rec_w, const float* __restrict__ rec_b,
                             float* __restrict__ bias2)
{
    int j = blockIdx.x * 256 + threadIdx.x;
    if (j < XO_DIM)
        bias2[j] = kernel_w[(size_t)H_DIM * XO_DIM + j] + kernel_b[j]
                 + rec_w[(size_t)H_DIM * XO_DIM + j] + rec_b[j];
}

// conv_w (o,h,w) -> Bt[(w*H+h)*H + o]
__global__ void transpose_convw_kernel(const float* __restrict__ conv_w, float* __restrict__ Bt)
{
    int id = blockIdx.x * 256 + threadIdx.x;
    if (id >= KCONV * H_DIM) return;
    int o = id % H_DIM;
    int rest = id / H_DIM;
    int h = rest % H_DIM;
    int w = rest / H_DIM;
    Bt[id] = conv_w[((size_t)o * H_DIM + h) * W_WIN + w];
}

// ---------------------------------------------------------------------------
// fp32 tiled GEMM: C = A(MxK) * B(KxN) + bias[n]   (row-major)
// MODE 0: plain + bias.  MODE 1: v = (AB+bias)*theme[m,n] + add[m,n]
// LHA: A(m,k) synthesized from h_all/local_dis (conv GEMM), k = w*H + h
// Requires: M % 128 == 0, K % 16 == 0. N edge-guarded.
// ---------------------------------------------------------------------------
template<int MODE, bool LHA>
__global__ __launch_bounds__(256, 2)
void gemm_kernel(const float* __restrict__ A, const float* __restrict__ Bm,
                 float* __restrict__ C, int M, int N, int K,
                 int lda, int ldb, int ldc,
                 const float* __restrict__ bias,
                 const float* __restrict__ themep,
                 const float* __restrict__ addp,
                 const float* __restrict__ hallp,
                 const float* __restrict__ ldwp)
{
    __shared__ float As[16][128];   // [k][m] (transposed)
    __shared__ float Bs[16][128];   // [k][n]
    const int tid = threadIdx.x;
    const int bn = blockIdx.x, bm = blockIdx.y;
    const int m0 = bm * 128, n0 = bn * 128;
    const int tx = tid & 15, ty = tid >> 4;
    const int arow = tid >> 1, acb = (tid & 1) * 8;     // A: 128 rows x 16 k
    const int brow = tid >> 4, bcb = (tid & 15) * 8;    // B: 16 k x 128 n

    float acc[8][8];
#pragma unroll
    for (int i = 0; i < 8; ++i)
#pragma unroll
        for (int j = 0; j < 8; ++j) acc[i][j] = 0.f;

    for (int k0 = 0; k0 < K; k0 += 16) {
        // ---- A tile ----
        float av[8];
        if constexpr (!LHA) {
            const float* ap = A + (size_t)(m0 + arow) * lda + k0 + acb;
            const float4 a0 = *(const float4*)ap;
            const float4 a1 = *(const float4*)(ap + 4);
            av[0] = a0.x; av[1] = a0.y; av[2] = a0.z; av[3] = a0.w;
            av[4] = a1.x; av[5] = a1.y; av[6] = a1.z; av[7] = a1.w;
        } else {
            const int m = m0 + arow;
            const int b = m >> 8, t = m & 255;
            const int k = k0 + acb;
            const int w = k / H_DIM;            // 16-chunk never straddles w (384 % 16 == 0)
            const int h = k - w * H_DIM;
            const int tp = t - (W_WIN - 1) + w;
            if (tp >= 0) {
                const float lw = ldwp[m * W_WIN + w];
                const float* hp = hallp + ((size_t)(b * T_DIM + tp)) * H_DIM + h;
                const float4 a0 = *(const float4*)hp;
                const float4 a1 = *(const float4*)(hp + 4);
                av[0] = a0.x * lw; av[1] = a0.y * lw; av[2] = a0.z * lw; av[3] = a0.w * lw;
                av[4] = a1.x * lw; av[5] = a1.y * lw; av[6] = a1.z * lw; av[7] = a1.w * lw;
            } else {
#pragma unroll
                for (int i = 0; i < 8; ++i) av[i] = 0.f;
            }
        }
#pragma unroll
        for (int i = 0; i < 8; ++i) As[acb + i][arow] = av[i];

        // ---- B tile (float2 loads; ldb always even here) ----
        {
            const float* bp = Bm + (size_t)(k0 + brow) * ldb + n0 + bcb;
            if (n0 + 127 < N) {
#pragma unroll
                for (int i = 0; i < 8; i += 2) {
                    const float2 b2 = *(const float2*)(bp + i);
                    Bs[brow][bcb + i] = b2.x;
                    Bs[brow][bcb + i + 1] = b2.y;
                }
            } else {
#pragma unroll
                for (int i = 0; i < 8; ++i)
                    Bs[brow][bcb + i] = (n0 + bcb + i < N) ? bp[i] : 0.f;
            }
        }
        __syncthreads();

#pragma unroll
        for (int kk = 0; kk < 16; ++kk) {
            float a[8], b[8];
#pragma unroll
            for (int i = 0; i < 8; ++i) a[i] = As[kk][ty * 8 + i];
#pragma unroll
            for (int j = 0; j < 8; ++j) b[j] = Bs[kk][tx * 8 + j];
#pragma unroll
            for (int i = 0; i < 8; ++i)
#pragma unroll
                for (int j = 0; j < 8; ++j)
                    acc[i][j] += a[i] * b[j];
        }
        __syncthreads();
    }

#pragma unroll
    for (int i = 0; i < 8; ++i) {
        const int m = m0 + ty * 8 + i;
#pragma unroll
        for (int j = 0; j < 8; ++j) {
            const int n = n0 + tx * 8 + j;
            if (n < N) {
                float v = acc[i][j];
                if (bias) v += bias[n];
                if constexpr (MODE == 1) {
                    const size_t idx = (size_t)m * ldc + n;
                    v = v * themep[idx] + addp[idx];
                }
                C[(size_t)m * ldc + n] = v;
            }
        }
    }
}

// ---------------------------------------------------------------------------
// one recurrence step.  grid = 64 blocks = 16 b-chunks(4 b) x 4 ch-chunks(32)
// each block computes, for its 4 batches, the 390 xo columns its ch-chunk
// needs (6 master-gate cols + 12 gate groups x 32), then the cell update.
// ---------------------------------------------------------------------------
#define BPB 4
#define CHC 32
#define NCOLS (6 + 12 * CHC)   // 390

__global__ __launch_bounds__(256)
void step_kernel(const float* __restrict__ Xproj, const float* __restrict__ rec_w,
                 float* __restrict__ h_all, float* __restrict__ c_buf,
                 float* __restrict__ dis_all, int t)
{
    __shared__ float h_s[BPB][H_DIM];
    __shared__ float xo_s[BPB][NCOLS];
    __shared__ float fm_s[BPB][3], im_s[BPB][3];

    const int tid = threadIdx.x;
    const int bc = blockIdx.x >> 2;
    const int cc = blockIdx.x & 3;
    const int ch0 = cc * CHC;
    const int b0 = bc * BPB;

    if (t > 0) {
        for (int i = tid; i < BPB * H_DIM; i += 256) {
            const int bl = i / H_DIM, h = i - bl * H_DIM;
            h_s[bl][h] = h_all[((size_t)(b0 + bl) * T_DIM + (t - 1)) * H_DIM + h];
        }
    }
    __syncthreads();

    // xo = Xproj[t] + h_{t-1} @ rec_w[0:H]
    for (int c = tid; c < NCOLS; c += 256) {
        int j;
        if (c < 6) j = c;
        else { const int a = (c - 6) >> 5, u = (c - 6) & 31; j = 6 + a * CH_DIM + ch0 + u; }
        float a0 = 0.f, a1 = 0.f, a2 = 0.f, a3 = 0.f;
        if (t > 0) {
            const float* rp = rec_w + j;
#pragma unroll 4
            for (int k = 0; k < H_DIM; ++k) {
                const float r = rp[(size_t)k * XO_DIM];
                a0 += h_s[0][k] * r;
                a1 += h_s[1][k] * r;
                a2 += h_s[2][k] * r;
                a3 += h_s[3][k] * r;
            }
        }
        const size_t xb = ((size_t)b0 * T_DIM + t) * XO_DIM + j;
        const size_t bstride = (size_t)T_DIM * XO_DIM;
        xo_s[0][c] = a0 + Xproj[xb];
        xo_s[1][c] = a1 + Xproj[xb + bstride];
        xo_s[2][c] = a2 + Xproj[xb + 2 * bstride];
        xo_s[3][c] = a3 + Xproj[xb + 3 * bstride];
    }
    __syncthreads();

    if (tid < BPB) {
        const int bl = tid;
        float x0 = xo_s[bl][0], x1 = xo_s[bl][1], x2 = xo_s[bl][2];
        float mx = fmaxf(x0, fmaxf(x1, x2));
        float e0 = expf(x0 - mx), e1 = expf(x1 - mx), e2 = expf(x2 - mx);
        float inv = 1.f / (e0 + e1 + e2);
        const float f0 = e0 * inv, f1 = (e0 + e1) * inv, f2 = (e0 + e1 + e2) * inv;
        fm_s[bl][0] = f0; fm_s[bl][1] = f1; fm_s[bl][2] = f2;
        x0 = xo_s[bl][3]; x1 = xo_s[bl][4]; x2 = xo_s[bl][5];
        mx = fmaxf(x0, fmaxf(x1, x2));
        e0 = expf(x0 - mx); e1 = expf(x1 - mx); e2 = expf(x2 - mx);
        inv = 1.f / (e0 + e1 + e2);
        im_s[bl][0] = (e0 + e1 + e2) * inv; im_s[bl][1] = (e1 + e2) * inv; im_s[bl][2] = e2 * inv;
        if (cc == 0)
            dis_all[(b0 + bl) * T_DIM + t] = 1.f - (f0 + f1 + f2) * (1.f / 3.f);
    }
    __syncthreads();

    for (int it = tid; it < BPB * 3 * CHC; it += 256) {
        const int bl = it / (3 * CHC);
        const int r = it - bl * (3 * CHC);
        const int l = r >> 5, u = r & 31;
        const float fm = fm_s[bl][l], im = im_s[bl][l];
        const float fg = sigmoidf_(xo_s[bl][6 + l * CHC + u]);
        const float ig = sigmoidf_(xo_s[bl][6 + (3 + l) * CHC + u]);
        const float og = sigmoidf_(xo_s[bl][6 + (6 + l) * CHC + u]);
        const float ci = tanhf(xo_s[bl][6 + (9 + l) * CHC + u]);
        const int hidx = l * CH_DIM + ch0 + u;
        const size_t cix = (size_t)(b0 + bl) * H_DIM + hidx;
        const float cl = (t > 0) ? c_buf[cix] : 0.f;
        const float ov = fm * im;
        const float cn = ov * (fg * cl + ig * ci) + (fm - ov) * cl + (im - ov) * ci;
        c_buf[cix] = cn;
        h_all[((size_t)(b0 + bl) * T_DIM + t) * H_DIM + hidx] = og * tanhf(cn);
    }
}

// ---------------------------------------------------------------------------
// per (b,t): local_dis (softmax of cumsum of dis window) and theme MLP
// grid = 16384 blocks x 64 threads
// ---------------------------------------------------------------------------
__global__ __launch_bounds__(64)
void locdis_theme_kernel(const float* __restrict__ h_all, const float* __restrict__ dis_all,
                         const float* __restrict__ scale_w, const float* __restrict__ scale_b,
                         const float* __restrict__ rescale_w, const float* __restrict__ rescale_b,
                         float* __restrict__ ldw, float* __restrict__ theme)
{
    __shared__ float ld_s[W_WIN];
    __shared__ float mh_s[H_DIM];
    __shared__ float hid_s[64];
    const int m = blockIdx.x;
    const int b = m >> 8, t = m & 255;
    const int tid = threadIdx.x;

    if (tid == 0) {
        float cum = 0.f, c[W_WIN];
        for (int w = 0; w < W_WIN; ++w) {
            const int tp = t - (W_WIN - 1) + w;
            const float d = (tp >= 0) ? dis_all[b * T_DIM + tp] : 0.f;
            cum += d; c[w] = cum;
        }
        float mx = c[0];
        for (int w = 1; w < W_WIN; ++w) mx = fmaxf(mx, c[w]);
        float s = 0.f, e[W_WIN];
        for (int w = 0; w < W_WIN; ++w) { e[w] = expf(c[w] - mx); s += e[w]; }
        const float inv = 1.f / s;
        for (int w = 0; w < W_WIN; ++w) { ld_s[w] = e[w] * inv; ldw[(size_t)m * W_WIN + w] = e[w] * inv; }
    }
    __syncthreads();

    for (int h = tid; h < H_DIM; h += 64) {
        float acc = 0.f;
        for (int w = 0; w < W_WIN; ++w) {
            const int tp = t - (W_WIN - 1) + w;
            if (tp >= 0) acc += ld_s[w] * h_all[((size_t)(b * T_DIM + tp)) * H_DIM + h];
        }
        mh_s[h] = acc * (1.f / W_WIN);
    }
    __syncthreads();

    {
        float acc = scale_b[tid];
        for (int h = 0; h < H_DIM; ++h) acc += mh_s[h] * scale_w[h * 64 + tid];
        hid_s[tid] = fmaxf(acc, 0.f);
    }
    __syncthreads();

    for (int h = tid; h < H_DIM; h += 64) {
        float acc = rescale_b[h];
        for (int j = 0; j < 64; ++j) acc += hid_s[j] * rescale_w[j * H_DIM + h];
        theme[(size_t)m * H_DIM + h] = 1.f / (1.f + expf(-acc));
    }
}

// ---------------------------------------------------------------------------
extern "C" void kernel_launch(void* const* d_in, const int* in_sizes, int n_in,
                              void* d_out, int out_size, void* d_ws, size_t ws_size,
                              hipStream_t stream)
{
    const float* x         = (const float*)d_in[0];
    const float* dia_w     = (const float*)d_in[1];
    const float* dia_b     = (const float*)d_in[2];
    const float* kernel_w  = (const float*)d_in[3];
    const float* kernel_b  = (const float*)d_in[4];
    const float* rec_w     = (const float*)d_in[5];
    const float* rec_b     = (const float*)d_in[6];
    const float* scale_w   = (const float*)d_in[7];
    const float* scale_b   = (const float*)d_in[8];
    const float* rescale_w = (const float*)d_in[9];
    const float* rescale_b = (const float*)d_in[10];
    const float* conv_w    = (const float*)d_in[11];
    const float* conv_b    = (const float*)d_in[12];
    const float* out_w     = (const float*)d_in[13];
    const float* out_b     = (const float*)d_in[14];
    // d_in[15] = choice (always 0 = 'dia')

    float* ws = (float*)d_ws;
    size_t off = 0;
    float* embed  = ws + off; off += (size_t)M_DIM * H_DIM;    // reused as rnn
    float* Xproj  = ws + off; off += (size_t)M_DIM * XO_DIM;
    float* h_all  = ws + off; off += (size_t)M_DIM * H_DIM;
    float* theme  = ws + off; off += (size_t)M_DIM * H_DIM;
    float* ldw    = ws + off; off += (size_t)M_DIM * W_WIN;
    float* dis_all= ws + off; off += M_DIM;
    float* c_buf  = ws + off; off += (size_t)B_DIM * H_DIM;
    float* bias2  = ws + off; off += 2048;
    float* convWt = ws + off; off += (size_t)KCONV * H_DIM;
    (void)ws_size; (void)in_sizes; (void)n_in; (void)out_size;

    bias2_kernel<<<(XO_DIM + 255) / 256, 256, 0, stream>>>(kernel_w, kernel_b, rec_w, rec_b, bias2);
    transpose_convw_kernel<<<(KCONV * H_DIM + 255) / 256, 256, 0, stream>>>(conv_w, convWt);

    // embed = x @ dia_w + dia_b
    gemm_kernel<0, false><<<dim3(3, 128), 256, 0, stream>>>(
        x, dia_w, embed, M_DIM, H_DIM, ICD_DIM, ICD_DIM, H_DIM, H_DIM,
        dia_b, nullptr, nullptr, nullptr, nullptr);

    // Xproj = embed @ kernel_w[0:H] + (kernel_w[H] + kernel_b + rec_w[H] + rec_b)
    gemm_kernel<0, false><<<dim3(13, 128), 256, 0, stream>>>(
        embed, kernel_w, Xproj, M_DIM, XO_DIM, H_DIM, H_DIM, XO_DIM, XO_DIM,
        bias2, nullptr, nullptr, nullptr, nullptr);

    // sequential recurrence
    for (int t = 0; t < T_DIM; ++t)
        step_kernel<<<64, 256, 0, stream>>>(Xproj, rec_w, h_all, c_buf, dis_all, t);

    // local_dis + theme
    locdis_theme_kernel<<<M_DIM, 64, 0, stream>>>(
        h_all, dis_all, scale_w, scale_b, rescale_w, rescale_b, ldw, theme);

    // rnn = h_all + theme * (local_h (.) conv_w + conv_b)   [conv as GEMM, fused epilogue]
    gemm_kernel<1, true><<<dim3(3, 128), 256, 0, stream>>>(
        nullptr, convWt, embed /*rnn*/, M_DIM, H_DIM, KCONV, 0, H_DIM, H_DIM,
        conv_b, theme, h_all, h_all, ldw);

    // out = rnn @ out_w + out_b
    gemm_kernel<0, false><<<dim3(16, 128), 256, 0, stream>>>(
        embed, out_w, (float*)d_out, M_DIM, ICD_DIM, H_DIM, H_DIM, ICD_DIM, ICD_DIM,
        out_b, nullptr, nullptr, nullptr, nullptr);
}

// Round 2
// 5686.517 us; speedup vs baseline: 2.0221x; 2.0221x over previous
//
#include <hip/hip_runtime.h>
#include <hip/hip_bf16.h>
#include <cstdint>
#include <cstddef>

#define B_DIM   64
#define T_DIM   256
#define ICD_DIM 2000
#define H_DIM   384
#define CH_DIM  128
#define W_WIN   10
#define M_DIM   (B_DIM * T_DIM)         // 16384
#define XO_DIM  1542                    // 4H + 2L
#define XO_PAD  1664                    // 13*128
#define K_X     2016                    // 2000 padded to 63*32
#define KCONV   3840                    // H*W
#define N_OUTP  2048                    // 2000 padded to 16*128

typedef unsigned short ushort_t;
typedef unsigned int   uint_t;
typedef __attribute__((ext_vector_type(8))) short short8;
typedef __attribute__((ext_vector_type(4))) float f32x4;

__device__ __forceinline__ ushort_t f2bf(float v) {
    __hip_bfloat16 b = __float2bfloat16(v);
    ushort_t u; __builtin_memcpy(&u, &b, 2); return u;
}
__device__ __forceinline__ float bf2f(ushort_t u) {
    __hip_bfloat16 b; __builtin_memcpy(&b, &u, 2); return __bfloat162float(b);
}
__device__ __forceinline__ float sigmoidf_(float x) { return 1.f / (1.f + expf(-x)); }

// ---------------------------------------------------------------------------
// prep kernels: transpose + pad + bf16(-split) conversions of weights
// ---------------------------------------------------------------------------
__global__ void prep_dia(const float* __restrict__ dia_w, ushort_t* __restrict__ hi, ushort_t* __restrict__ lo)
{
    int id = blockIdx.x * 256 + threadIdx.x;
    if (id >= H_DIM * K_X) return;
    int n = id / K_X, k = id - n * K_X;
    float v = (k < ICD_DIM) ? dia_w[(size_t)k * H_DIM + n] : 0.f;
    ushort_t h = f2bf(v);
    hi[id] = h; lo[id] = f2bf(v - bf2f(h));
}
__global__ void prep_ker(const float* __restrict__ kernel_w, ushort_t* __restrict__ hi, ushort_t* __restrict__ lo)
{
    int id = blockIdx.x * 256 + threadIdx.x;
    if (id >= XO_PAD * H_DIM) return;
    int n = id / H_DIM, k = id - n * H_DIM;
    float v = (n < XO_DIM) ? kernel_w[(size_t)k * XO_DIM + n] : 0.f;
    ushort_t h = f2bf(v);
    hi[id] = h; lo[id] = f2bf(v - bf2f(h));
}
__global__ void prep_conv(const float* __restrict__ conv_w, ushort_t* __restrict__ bt)
{
    int id = blockIdx.x * 256 + threadIdx.x;
    if (id >= H_DIM * KCONV) return;
    int o = id / KCONV, k = id - o * KCONV;
    int w = k / H_DIM, h = k - w * H_DIM;
    bt[id] = f2bf(conv_w[((size_t)o * H_DIM + h) * W_WIN + w]);
}
__global__ void prep_out(const float* __restrict__ out_w, ushort_t* __restrict__ bt)
{
    int id = blockIdx.x * 256 + threadIdx.x;
    if (id >= N_OUTP * H_DIM) return;
    int n = id / H_DIM, k = id - n * H_DIM;
    bt[id] = f2bf((n < ICD_DIM) ? out_w[(size_t)k * ICD_DIM + n] : 0.f);
}
__global__ void prep_misc(const float* __restrict__ kernel_w, const float* __restrict__ kernel_b,
                          const float* __restrict__ rec_w, const float* __restrict__ rec_b,
                          const float* __restrict__ out_b,
                          float* __restrict__ bias2p, float* __restrict__ outbp)
{
    int j = blockIdx.x * 256 + threadIdx.x;
    if (j < XO_PAD)
        bias2p[j] = (j < XO_DIM) ? (kernel_w[(size_t)H_DIM * XO_DIM + j] + kernel_b[j]
                                  + rec_w[(size_t)H_DIM * XO_DIM + j] + rec_b[j]) : 0.f;
    if (j < N_OUTP)
        outbp[j] = (j < ICD_DIM) ? out_b[j] : 0.f;
}

// ---------------------------------------------------------------------------
// MFMA bf16 GEMM, 128x128 tile, BK=32, 256 threads (4 waves, 2x2 wave grid).
// LDS fragment layout [kq][rc][8] -> conflict-free ds_read_b128.
// MODE 0: A = x (f32, split hi/lo on the fly, K pad 2016), B = dia hi/lo,
//         out: Ehi/Elo bf16 (embed split) with +dia_b.
// MODE 1: A = Ehi/Elo, B = ker hi/lo, out: Xproj f32 (+bias2), guard n<1542.
// MODE 2: A = local_h synth (h_all*ldw -> bf16), B = convT,
//         out: rnn_bf = bf16((acc+conv_b)*theme + h_all).
// MODE 3: A = rnn_bf, B = outwT, out: d_out f32 (+out_b), guard n<2000.
// ---------------------------------------------------------------------------
template<int MODE>
__global__ __launch_bounds__(256)
void mfma_gemm(const float* __restrict__ Af,
               const ushort_t* __restrict__ Abh, const ushort_t* __restrict__ Abl,
               const ushort_t* __restrict__ Bh, const ushort_t* __restrict__ Bl,
               float* __restrict__ Cf, ushort_t* __restrict__ Cb,
               ushort_t* __restrict__ Ehi, ushort_t* __restrict__ Elo,
               const float* __restrict__ bias,
               const ushort_t* __restrict__ theme,
               const float* __restrict__ hall, const float* __restrict__ ldwp,
               int ksteps, int kdim)
{
    constexpr bool SPLIT = (MODE <= 1);
    __shared__ ushort_t AhS[4096];
    __shared__ ushort_t BhS[4096];
    __shared__ ushort_t AlS[4096];
    __shared__ ushort_t BlS[4096];

    const int tid = threadIdx.x;
    const int rc = tid & 127, kh = tid >> 7;
    const int m0 = blockIdx.y * 128, n0 = blockIdx.x * 128;
    const int kq0 = kh * 2;

    const int lane = tid & 63, wid = tid >> 6;
    const int wm = wid >> 1, wn = wid & 1;
    const int l15 = lane & 15, lkq = lane >> 4;

    f32x4 acc[4][4];
#pragma unroll
    for (int i = 0; i < 4; ++i)
#pragma unroll
        for (int j = 0; j < 4; ++j)
#pragma unroll
            for (int q = 0; q < 4; ++q) acc[i][j][q] = 0.f;

    for (int ks = 0; ks < ksteps; ++ks) {
        const int k16 = ks * 32 + kh * 16;
        __syncthreads();

        // ---------------- A stage ----------------
        if constexpr (MODE == 0 || MODE == 2) {
            float v[16];
            bool ok;
            if constexpr (MODE == 0) {
                ok = (k16 < ICD_DIM);
                if (ok) {
                    const float* ap = Af + (size_t)(m0 + rc) * ICD_DIM + k16;
#pragma unroll
                    for (int q = 0; q < 4; ++q) {
                        float4 t = *(const float4*)(ap + q * 4);
                        v[q * 4 + 0] = t.x; v[q * 4 + 1] = t.y; v[q * 4 + 2] = t.z; v[q * 4 + 3] = t.w;
                    }
                }
            } else {
                const int w = k16 / H_DIM, h0i = k16 - (k16 / H_DIM) * H_DIM;
                const int gm = m0 + rc, b = gm >> 8, tt = gm & 255;
                const int tp = tt - (W_WIN - 1) + w;
                ok = (tp >= 0);
                if (ok) {
                    const float lw = ldwp[(size_t)gm * W_WIN + w];
                    const float* ap = hall + ((size_t)(b * T_DIM + tp)) * H_DIM + h0i;
#pragma unroll
                    for (int q = 0; q < 4; ++q) {
                        float4 t = *(const float4*)(ap + q * 4);
                        v[q * 4 + 0] = t.x * lw; v[q * 4 + 1] = t.y * lw;
                        v[q * 4 + 2] = t.z * lw; v[q * 4 + 3] = t.w * lw;
                    }
                }
            }
            if (!ok) {
#pragma unroll
                for (int q = 0; q < 16; ++q) v[q] = 0.f;
            }
            uint_t hh[8], ll[8];
#pragma unroll
            for (int i = 0; i < 8; ++i) {
                ushort_t h0 = f2bf(v[2 * i]), h1 = f2bf(v[2 * i + 1]);
                hh[i] = (uint_t)h0 | ((uint_t)h1 << 16);
                if constexpr (SPLIT) {
                    ushort_t l0 = f2bf(v[2 * i] - bf2f(h0)), l1 = f2bf(v[2 * i + 1] - bf2f(h1));
                    ll[i] = (uint_t)l0 | ((uint_t)l1 << 16);
                }
            }
            *(uint4*)&AhS[(kq0 * 128 + rc) * 8]       = make_uint4(hh[0], hh[1], hh[2], hh[3]);
            *(uint4*)&AhS[((kq0 + 1) * 128 + rc) * 8] = make_uint4(hh[4], hh[5], hh[6], hh[7]);
            if constexpr (SPLIT) {
                *(uint4*)&AlS[(kq0 * 128 + rc) * 8]       = make_uint4(ll[0], ll[1], ll[2], ll[3]);
                *(uint4*)&AlS[((kq0 + 1) * 128 + rc) * 8] = make_uint4(ll[4], ll[5], ll[6], ll[7]);
            }
        } else {
            const ushort_t* ap = ((MODE == 1) ? Ehi : Abh) + (size_t)(m0 + rc) * H_DIM + k16;
            *(uint4*)&AhS[(kq0 * 128 + rc) * 8]       = *(const uint4*)ap;
            *(uint4*)&AhS[((kq0 + 1) * 128 + rc) * 8] = *(const uint4*)(ap + 8);
            if constexpr (MODE == 1) {
                const ushort_t* ap2 = Elo + (size_t)(m0 + rc) * H_DIM + k16;
                *(uint4*)&AlS[(kq0 * 128 + rc) * 8]       = *(const uint4*)ap2;
                *(uint4*)&AlS[((kq0 + 1) * 128 + rc) * 8] = *(const uint4*)(ap2 + 8);
            }
        }

        // ---------------- B stage ----------------
        {
            const ushort_t* bp = Bh + (size_t)(n0 + rc) * kdim + k16;
            *(uint4*)&BhS[(kq0 * 128 + rc) * 8]       = *(const uint4*)bp;
            *(uint4*)&BhS[((kq0 + 1) * 128 + rc) * 8] = *(const uint4*)(bp + 8);
            if constexpr (SPLIT) {
                const ushort_t* bp2 = Bl + (size_t)(n0 + rc) * kdim + k16;
                *(uint4*)&BlS[(kq0 * 128 + rc) * 8]       = *(const uint4*)bp2;
                *(uint4*)&BlS[((kq0 + 1) * 128 + rc) * 8] = *(const uint4*)(bp2 + 8);
            }
        }
        __syncthreads();

        // ---------------- MFMA ----------------
        short8 ah[4], bh[4], al[4], bl[4];
#pragma unroll
        for (int mf = 0; mf < 4; ++mf)
            ah[mf] = *(const short8*)&AhS[(lkq * 128 + wm * 64 + mf * 16 + l15) * 8];
#pragma unroll
        for (int nf = 0; nf < 4; ++nf)
            bh[nf] = *(const short8*)&BhS[(lkq * 128 + wn * 64 + nf * 16 + l15) * 8];
        if constexpr (SPLIT) {
#pragma unroll
            for (int mf = 0; mf < 4; ++mf)
                al[mf] = *(const short8*)&AlS[(lkq * 128 + wm * 64 + mf * 16 + l15) * 8];
#pragma unroll
            for (int nf = 0; nf < 4; ++nf)
                bl[nf] = *(const short8*)&BlS[(lkq * 128 + wn * 64 + nf * 16 + l15) * 8];
        }
#pragma unroll
        for (int mf = 0; mf < 4; ++mf)
#pragma unroll
            for (int nf = 0; nf < 4; ++nf) {
                acc[mf][nf] = __builtin_amdgcn_mfma_f32_16x16x32_bf16(ah[mf], bh[nf], acc[mf][nf], 0, 0, 0);
                if constexpr (SPLIT) {
                    acc[mf][nf] = __builtin_amdgcn_mfma_f32_16x16x32_bf16(ah[mf], bl[nf], acc[mf][nf], 0, 0, 0);
                    acc[mf][nf] = __builtin_amdgcn_mfma_f32_16x16x32_bf16(al[mf], bh[nf], acc[mf][nf], 0, 0, 0);
                }
            }
    }

    // ---------------- epilogue ----------------
#pragma unroll
    for (int mf = 0; mf < 4; ++mf)
#pragma unroll
        for (int nf = 0; nf < 4; ++nf)
#pragma unroll
            for (int j = 0; j < 4; ++j) {
                const int gm = m0 + wm * 64 + mf * 16 + lkq * 4 + j;
                const int gn = n0 + wn * 64 + nf * 16 + l15;
                float v = acc[mf][nf][j] + bias[gn];
                if constexpr (MODE == 0) {
                    ushort_t h = f2bf(v);
                    Ehi[(size_t)gm * H_DIM + gn] = h;
                    Elo[(size_t)gm * H_DIM + gn] = f2bf(v - bf2f(h));
                } else if constexpr (MODE == 1) {
                    if (gn < XO_DIM) Cf[(size_t)gm * XO_DIM + gn] = v;
                } else if constexpr (MODE == 2) {
                    const size_t ix = (size_t)gm * H_DIM + gn;
                    v = v * bf2f(theme[ix]) + hall[ix];
                    Cb[ix] = f2bf(v);
                } else {
                    if (gn < ICD_DIM) Cf[(size_t)gm * ICD_DIM + gn] = v;
                }
            }
}

// ---------------------------------------------------------------------------
// recurrence step: 256 blocks = 32 b-chunks(2 batches) x 8 ch-chunks(16)
// ---------------------------------------------------------------------------
#define SCHC 16
#define SNCOLS (6 + 12 * SCHC)   // 198

__global__ __launch_bounds__(256)
void step_kernel(const float* __restrict__ Xproj, const float* __restrict__ rec_w,
                 float* __restrict__ h_all, float* __restrict__ c_buf,
                 float* __restrict__ dis_all, int t)
{
    __shared__ float h_s[H_DIM * 2];          // [k][2]
    __shared__ float xo_s[SNCOLS][2];
    __shared__ float fm_s[2][3], im_s[2][3];

    const int tid = threadIdx.x;
    const int bc = blockIdx.x >> 3, cc = blockIdx.x & 7;
    const int b0 = bc * 2, ch0 = cc * SCHC;

    if (t > 0) {
        for (int i = tid; i < 2 * H_DIM; i += 256) {
            const int k = i >> 1, bb = i & 1;
            h_s[i] = h_all[((size_t)(b0 + bb) * T_DIM + (t - 1)) * H_DIM + k];
        }
    }
    __syncthreads();

    if (tid < SNCOLS) {
        const int c = tid;
        const int j = (c < 6) ? c : 6 + ((c - 6) >> 4) * CH_DIM + ch0 + ((c - 6) & 15);
        float a0 = 0.f, a1 = 0.f;
        if (t > 0) {
            const float* rp = rec_w + j;
#pragma unroll 4
            for (int k = 0; k < H_DIM; ++k) {
                const float r = rp[(size_t)k * XO_DIM];
                const float2 h2 = *(const float2*)&h_s[k * 2];
                a0 += h2.x * r; a1 += h2.y * r;
            }
        }
        const size_t xb = ((size_t)b0 * T_DIM + t) * XO_DIM + j;
        xo_s[c][0] = a0 + Xproj[xb];
        xo_s[c][1] = a1 + Xproj[xb + (size_t)T_DIM * XO_DIM];
    }
    __syncthreads();

    if (tid < 2) {
        const int bb = tid;
        float x0 = xo_s[0][bb], x1 = xo_s[1][bb], x2 = xo_s[2][bb];
        float mx = fmaxf(x0, fmaxf(x1, x2));
        float e0 = expf(x0 - mx), e1 = expf(x1 - mx), e2 = expf(x2 - mx);
        float inv = 1.f / (e0 + e1 + e2);
        const float f0 = e0 * inv, f1 = (e0 + e1) * inv, f2 = 1.f;
        fm_s[bb][0] = f0; fm_s[bb][1] = f1; fm_s[bb][2] = f2;
        x0 = xo_s[3][bb]; x1 = xo_s[4][bb]; x2 = xo_s[5][bb];
        mx = fmaxf(x0, fmaxf(x1, x2));
        e0 = expf(x0 - mx); e1 = expf(x1 - mx); e2 = expf(x2 - mx);
        inv = 1.f / (e0 + e1 + e2);
        im_s[bb][0] = 1.f; im_s[bb][1] = (e1 + e2) * inv; im_s[bb][2] = e2 * inv;
        if (cc == 0)
            dis_all[(b0 + bb) * T_DIM + t] = 1.f - (f0 + f1 + f2) * (1.f / 3.f);
    }
    __syncthreads();

    if (tid < 2 * 3 * SCHC) {
        const int bb = tid / (3 * SCHC);
        const int r = tid - bb * (3 * SCHC);
        const int l = r >> 4, u = r & 15;
        const float fm = fm_s[bb][l], im = im_s[bb][l];
        const float fg = sigmoidf_(xo_s[6 + (l) * SCHC + u][bb]);
        const float ig = sigmoidf_(xo_s[6 + (3 + l) * SCHC + u][bb]);
        const float og = sigmoidf_(xo_s[6 + (6 + l) * SCHC + u][bb]);
        const float ci = tanhf(xo_s[6 + (9 + l) * SCHC + u][bb]);
        const int hidx = l * CH_DIM + ch0 + u;
        const size_t cix = (size_t)(b0 + bb) * H_DIM + hidx;
        const float cl = (t > 0) ? c_buf[cix] : 0.f;
        const float ov = fm * im;
        const float cn = ov * (fg * cl + ig * ci) + (fm - ov) * cl + (im - ov) * ci;
        c_buf[cix] = cn;
        h_all[((size_t)(b0 + bb) * T_DIM + t) * H_DIM + hidx] = og * tanhf(cn);
    }
}

// ---------------------------------------------------------------------------
// per (b,t): local_dis weights + theme MLP
// ---------------------------------------------------------------------------
__global__ __launch_bounds__(64)
void locdis_theme_kernel(const float* __restrict__ h_all, const float* __restrict__ dis_all,
                         const float* __restrict__ scale_w, const float* __restrict__ scale_b,
                         const float* __restrict__ rescale_w, const float* __restrict__ rescale_b,
                         float* __restrict__ ldw, ushort_t* __restrict__ theme)
{
    __shared__ float ld_s[W_WIN];
    __shared__ float mh_s[H_DIM];
    __shared__ float hid_s[64];
    const int m = blockIdx.x;
    const int b = m >> 8, t = m & 255;
    const int tid = threadIdx.x;

    if (tid == 0) {
        float cum = 0.f, c[W_WIN];
        for (int w = 0; w < W_WIN; ++w) {
            const int tp = t - (W_WIN - 1) + w;
            cum += (tp >= 0) ? dis_all[b * T_DIM + tp] : 0.f;
            c[w] = cum;
        }
        float mx = c[0];
        for (int w = 1; w < W_WIN; ++w) mx = fmaxf(mx, c[w]);
        float s = 0.f, e[W_WIN];
        for (int w = 0; w < W_WIN; ++w) { e[w] = expf(c[w] - mx); s += e[w]; }
        const float inv = 1.f / s;
        for (int w = 0; w < W_WIN; ++w) { ld_s[w] = e[w] * inv; ldw[(size_t)m * W_WIN + w] = e[w] * inv; }
    }
    __syncthreads();

    for (int h = tid; h < H_DIM; h += 64) {
        float acc = 0.f;
        for (int w = 0; w < W_WIN; ++w) {
            const int tp = t - (W_WIN - 1) + w;
            if (tp >= 0) acc += ld_s[w] * h_all[((size_t)(b * T_DIM + tp)) * H_DIM + h];
        }
        mh_s[h] = acc * (1.f / W_WIN);
    }
    __syncthreads();

    {
        float acc = scale_b[tid];
        for (int h = 0; h < H_DIM; ++h) acc += mh_s[h] * scale_w[h * 64 + tid];
        hid_s[tid] = fmaxf(acc, 0.f);
    }
    __syncthreads();

    for (int h = tid; h < H_DIM; h += 64) {
        float acc = rescale_b[h];
        for (int j = 0; j < 64; ++j) acc += hid_s[j] * rescale_w[j * H_DIM + h];
        theme[(size_t)m * H_DIM + h] = f2bf(sigmoidf_(acc));
    }
}

// ---------------------------------------------------------------------------
extern "C" void kernel_launch(void* const* d_in, const int* in_sizes, int n_in,
                              void* d_out, int out_size, void* d_ws, size_t ws_size,
                              hipStream_t stream)
{
    const float* x         = (const float*)d_in[0];
    const float* dia_w     = (const float*)d_in[1];
    const float* dia_b     = (const float*)d_in[2];
    const float* kernel_w  = (const float*)d_in[3];
    const float* kernel_b  = (const float*)d_in[4];
    const float* rec_w     = (const float*)d_in[5];
    const float* rec_b     = (const float*)d_in[6];
    const float* scale_w   = (const float*)d_in[7];
    const float* scale_b   = (const float*)d_in[8];
    const float* rescale_w = (const float*)d_in[9];
    const float* rescale_b = (const float*)d_in[10];
    const float* conv_w    = (const float*)d_in[11];
    const float* conv_b    = (const float*)d_in[12];
    const float* out_w     = (const float*)d_in[13];
    const float* out_b     = (const float*)d_in[14];
    (void)in_sizes; (void)n_in; (void)out_size; (void)ws_size;

    float* ws = (float*)d_ws;
    size_t off = 0;
    float* Xproj   = ws + off; off += (size_t)M_DIM * XO_DIM;     // 25.26M f
    float* h_all   = ws + off; off += (size_t)M_DIM * H_DIM;
    float* ldw     = ws + off; off += (size_t)M_DIM * W_WIN;
    float* dis_all = ws + off; off += M_DIM;
    float* c_buf   = ws + off; off += (size_t)B_DIM * H_DIM;
    float* bias2p  = ws + off; off += XO_PAD;
    float* outbp   = ws + off; off += N_OUTP;
    ushort_t* us = (ushort_t*)(ws + off);
    size_t uo = 0;
    ushort_t* dia_hi = us + uo; uo += (size_t)H_DIM * K_X;
    ushort_t* dia_lo = us + uo; uo += (size_t)H_DIM * K_X;
    ushort_t* ker_hi = us + uo; uo += (size_t)XO_PAD * H_DIM;
    ushort_t* ker_lo = us + uo; uo += (size_t)XO_PAD * H_DIM;
    ushort_t* conv_t = us + uo; uo += (size_t)H_DIM * KCONV;
    ushort_t* outw_t = us + uo; uo += (size_t)N_OUTP * H_DIM;
    ushort_t* ehi    = us + uo; uo += (size_t)M_DIM * H_DIM;
    ushort_t* elo    = us + uo; uo += (size_t)M_DIM * H_DIM;
    ushort_t* themeb = us + uo; uo += (size_t)M_DIM * H_DIM;
    ushort_t* rnnb   = us + uo; uo += (size_t)M_DIM * H_DIM;

    // --- prep ---
    prep_dia <<<(H_DIM * K_X + 255) / 256, 256, 0, stream>>>(dia_w, dia_hi, dia_lo);
    prep_ker <<<(XO_PAD * H_DIM + 255) / 256, 256, 0, stream>>>(kernel_w, ker_hi, ker_lo);
    prep_conv<<<(H_DIM * KCONV + 255) / 256, 256, 0, stream>>>(conv_w, conv_t);
    prep_out <<<(N_OUTP * H_DIM + 255) / 256, 256, 0, stream>>>(out_w, outw_t);
    prep_misc<<<(N_OUTP + 255) / 256, 256, 0, stream>>>(kernel_w, kernel_b, rec_w, rec_b, out_b, bias2p, outbp);

    // --- embed = x @ dia_w + dia_b  (bf16x3, writes hi/lo split) ---
    mfma_gemm<0><<<dim3(3, 128), 256, 0, stream>>>(
        x, nullptr, nullptr, dia_hi, dia_lo, nullptr, nullptr, ehi, elo,
        dia_b, nullptr, nullptr, nullptr, K_X / 32, K_X);

    // --- Xproj = embed @ kernel_w + bias2  (bf16x3) ---
    mfma_gemm<1><<<dim3(13, 128), 256, 0, stream>>>(
        nullptr, nullptr, nullptr, ker_hi, ker_lo, Xproj, nullptr, ehi, elo,
        bias2p, nullptr, nullptr, nullptr, H_DIM / 32, H_DIM);

    // --- sequential recurrence ---
    for (int t = 0; t < T_DIM; ++t)
        step_kernel<<<256, 256, 0, stream>>>(Xproj, rec_w, h_all, c_buf, dis_all, t);

    // --- local_dis + theme ---
    locdis_theme_kernel<<<M_DIM, 64, 0, stream>>>(
        h_all, dis_all, scale_w, scale_b, rescale_w, rescale_b, ldw, themeb);

    // --- rnn_bf = bf16( (local_h . conv_w + conv_b) * theme + h_all ) ---
    mfma_gemm<2><<<dim3(3, 128), 256, 0, stream>>>(
        nullptr, nullptr, nullptr, conv_t, nullptr, nullptr, rnnb, nullptr, nullptr,
        conv_b, themeb, h_all, ldw, KCONV / 32, KCONV);

    // --- out = rnn @ out_w + out_b ---
    mfma_gemm<3><<<dim3(16, 128), 256, 0, stream>>>(
        nullptr, rnnb, nullptr, outw_t, nullptr, (float*)d_out, nullptr, nullptr, nullptr,
        outbp, nullptr, nullptr, nullptr, H_DIM / 32, H_DIM);
}